// Round 1
// baseline (630.753 us; speedup 1.0000x reference)
//
#include <hip/hip_runtime.h>
#include <hip/hip_bf16.h>

// Problem constants (match reference)
#define BB 32
#define SS 2048
#define HH 1024
#define CC 5
#define TEMP_INV (1.0f/0.07f)

// ---------------------------------------------------------------------------
// K1: pooling weights — softmax over S of sum(logits[:,:,1:5])
// grid: 64 blocks = (b, which), block: 256
__global__ void pool_weights(const float* __restrict__ alog,
                             const float* __restrict__ olog,
                             float* __restrict__ w_a,
                             float* __restrict__ w_o) {
    int b = blockIdx.x >> 1;
    int which = blockIdx.x & 1;
    const float* lg = which ? olog : alog;
    float* wout = which ? w_o : w_a;
    __shared__ float sl[SS];
    __shared__ float red[256];
    int t = threadIdx.x;
    for (int s = t; s < SS; s += 256) {
        const float* p = lg + ((size_t)b * SS + s) * CC;
        sl[s] = p[1] + p[2] + p[3] + p[4];
    }
    __syncthreads();
    // max-reduce
    float m = -1e30f;
    for (int s = t; s < SS; s += 256) m = fmaxf(m, sl[s]);
    red[t] = m;
    __syncthreads();
    for (int o = 128; o > 0; o >>= 1) {
        if (t < o) red[t] = fmaxf(red[t], red[t + o]);
        __syncthreads();
    }
    m = red[0];
    __syncthreads();
    // exp + sum-reduce (store exp back into sl)
    float sum = 0.f;
    for (int s = t; s < SS; s += 256) {
        float e = expf(sl[s] - m);
        sl[s] = e;
        sum += e;
    }
    red[t] = sum;
    __syncthreads();
    for (int o = 128; o > 0; o >>= 1) {
        if (t < o) red[t] += red[t + o];
        __syncthreads();
    }
    float inv = 1.0f / red[0];
    for (int s = t; s < SS; s += 256) wout[(size_t)b * SS + s] = sl[s] * inv;
}

// ---------------------------------------------------------------------------
// K2: pooling main pass — part[chunk][b][h] = sum over 256 s of span*w
// grid: 256 blocks = (b, chunk of 8), block: 256 threads, 4 h each (float4)
__global__ void pool_partial(const float* __restrict__ span,
                             const float* __restrict__ w_a,
                             const float* __restrict__ w_o,
                             float* __restrict__ part_a,
                             float* __restrict__ part_o) {
    int b = blockIdx.x >> 3;
    int chunk = blockIdx.x & 7;
    int t = threadIdx.x;
    __shared__ float wa[256], wo[256];
    int s0 = chunk * 256;
    wa[t] = w_a[(size_t)b * SS + s0 + t];
    wo[t] = w_o[(size_t)b * SS + s0 + t];
    __syncthreads();
    const float4* sp = (const float4*)span + ((size_t)b * SS + s0) * (HH / 4) + t;
    float4 aa = {0.f, 0.f, 0.f, 0.f};
    float4 oo = {0.f, 0.f, 0.f, 0.f};
    for (int ss = 0; ss < 256; ++ss) {
        float4 v = sp[(size_t)ss * (HH / 4)];
        float fa = wa[ss], fo = wo[ss];
        aa.x += v.x * fa; aa.y += v.y * fa; aa.z += v.z * fa; aa.w += v.w * fa;
        oo.x += v.x * fo; oo.y += v.y * fo; oo.z += v.z * fo; oo.w += v.w * fo;
    }
    size_t idx = ((size_t)chunk * BB + b) * HH + (size_t)t * 4;
    *(float4*)(part_a + idx) = aa;
    *(float4*)(part_o + idx) = oo;
}

// K2r: reduce 8 partials -> a_emb/o_emb [32][1024]
// grid: 256, block: 256  (gid 0..65535; which = hi bit)
__global__ void pool_reduce(const float* __restrict__ part_a,
                            const float* __restrict__ part_o,
                            float* __restrict__ a_emb,
                            float* __restrict__ o_emb) {
    int gid = blockIdx.x * 256 + threadIdx.x;
    int which = gid >> 15;
    int r = gid & 32767;
    const float* p = which ? part_o : part_a;
    float s = 0.f;
    for (int c = 0; c < 8; ++c) s += p[(size_t)c * 32768 + r];
    (which ? o_emb : a_emb)[r] = s;
}

// ---------------------------------------------------------------------------
// K3: a_h = relu(a_emb@Wa1+ba1), o_h = relu(o_emb@Wo1+bo1)   [32][512]
// grid: 128 = which(2) x b(32) x jt(2), block: 256
__global__ void layer1_ao(const float* __restrict__ a_emb, const float* __restrict__ o_emb,
                          const float* __restrict__ Wa1, const float* __restrict__ ba1,
                          const float* __restrict__ Wo1, const float* __restrict__ bo1,
                          float* __restrict__ a_h, float* __restrict__ o_h) {
    int which = blockIdx.x >> 6;
    int b = (blockIdx.x >> 1) & 31;
    int jt = blockIdx.x & 1;
    const float* emb = (which ? o_emb : a_emb) + (size_t)b * HH;
    const float* W = which ? Wo1 : Wa1;
    const float* bias = which ? bo1 : ba1;
    float* out = (which ? o_h : a_h) + (size_t)b * 512;
    __shared__ float x[HH];
    int t = threadIdx.x;
    for (int k = t; k < HH; k += 256) x[k] = emb[k];
    __syncthreads();
    int j = jt * 256 + t;
    float acc = bias[j];
    for (int k = 0; k < HH; ++k) acc += x[k] * W[(size_t)k * 512 + j];
    out[j] = fmaxf(acc, 0.f);
}

// K4: a_proj = l2norm(a_h@Wa2+ba2), same for o   [32][128]
// grid: 64 = which(2) x b(32), block: 128
__global__ void layer2_ao(const float* __restrict__ a_h, const float* __restrict__ o_h,
                          const float* __restrict__ Wa2, const float* __restrict__ ba2,
                          const float* __restrict__ Wo2, const float* __restrict__ bo2,
                          float* __restrict__ a_proj, float* __restrict__ o_proj) {
    int which = blockIdx.x >> 5;
    int b = blockIdx.x & 31;
    const float* h = (which ? o_h : a_h) + (size_t)b * 512;
    const float* W = which ? Wo2 : Wa2;
    const float* bias = which ? bo2 : ba2;
    float* out = (which ? o_proj : a_proj) + (size_t)b * 128;
    __shared__ float x[512];
    __shared__ float red[128];
    int t = threadIdx.x;
    for (int k = t; k < 512; k += 128) x[k] = h[k];
    __syncthreads();
    float acc = bias[t];
    for (int k = 0; k < 512; ++k) acc += x[k] * W[(size_t)k * 128 + t];
    red[t] = acc * acc;
    __syncthreads();
    for (int o = 64; o > 0; o >>= 1) {
        if (t < o) red[t] += red[t + o];
        __syncthreads();
    }
    float n = fmaxf(sqrtf(red[0]), 1e-12f);
    out[t] = acc / n;
}

// K5: s_h = relu(concat(a_emb,o_emb)@Ws1+bs1)   [32][1024]
// grid: 128 = b(32) x jt(4), block: 256
__global__ void layer1_s(const float* __restrict__ a_emb, const float* __restrict__ o_emb,
                         const float* __restrict__ Ws1, const float* __restrict__ bs1,
                         float* __restrict__ s_h) {
    int b = blockIdx.x >> 2;
    int jt = blockIdx.x & 3;
    __shared__ float x[2 * HH];
    int t = threadIdx.x;
    for (int k = t; k < HH; k += 256) {
        x[k] = a_emb[(size_t)b * HH + k];
        x[HH + k] = o_emb[(size_t)b * HH + k];
    }
    __syncthreads();
    int j = jt * 256 + t;
    float acc = bs1[j];
    for (int k = 0; k < 2 * HH; ++k) acc += x[k] * Ws1[(size_t)k * HH + j];
    s_h[(size_t)b * HH + j] = fmaxf(acc, 0.f);
}

// K6: s_proj = l2norm(s_h@Ws2+bs2)   [32][256]
// grid: 32, block: 256
__global__ void layer2_s(const float* __restrict__ s_h, const float* __restrict__ Ws2,
                         const float* __restrict__ bs2, float* __restrict__ s_proj) {
    int b = blockIdx.x;
    __shared__ float x[HH];
    __shared__ float red[256];
    int t = threadIdx.x;
    for (int k = t; k < HH; k += 256) x[k] = s_h[(size_t)b * HH + k];
    __syncthreads();
    float acc = bs2[t];
    for (int k = 0; k < HH; ++k) acc += x[k] * Ws2[(size_t)k * 256 + t];
    red[t] = acc * acc;
    __syncthreads();
    for (int o = 128; o > 0; o >>= 1) {
        if (t < o) red[t] += red[t + o];
        __syncthreads();
    }
    float n = fmaxf(sqrtf(red[0]), 1e-12f);
    s_proj[(size_t)b * 256 + t] = acc / n;
}

// ---------------------------------------------------------------------------
// K7: losses. One block, 1024 threads: thread (i,j) = one 32x32 sim entry.
__global__ void loss_kernel(const float* __restrict__ a_proj,
                            const float* __restrict__ o_proj,
                            const float* __restrict__ s_proj,
                            const int* __restrict__ labels,
                            float* __restrict__ out) {
    __shared__ float ap[BB * 128];
    __shared__ float op[BB * 128];
    __shared__ float sp[BB * 256];
    __shared__ float rowv[BB], rownt[BB];
    __shared__ int hp[BB], lab[BB];
    int t = threadIdx.x;
    for (int i = t; i < BB * 128; i += 1024) { ap[i] = a_proj[i]; op[i] = o_proj[i]; }
    for (int i = t; i < BB * 256; i += 1024) sp[i] = s_proj[i];
    if (t < BB) lab[t] = labels[t];
    __syncthreads();
    int i = t >> 5, j = t & 31;

    // re-normalize sp rows (reference calls _l2norm again inside _ntxent)
    float ssq = 0.f;
    for (int k = 0; k < 8; ++k) {
        float v = sp[i * 256 + j * 8 + k];
        ssq += v * v;
    }
    for (int m = 16; m > 0; m >>= 1) ssq += __shfl_xor(ssq, m, 64);
    float inv = 1.0f / fmaxf(sqrtf(ssq), 1e-12f);
    for (int k = j; k < 256; k += 32) sp[i * 256 + k] *= inv;
    __syncthreads();

    // infonce: sim = a_proj @ o_proj.T / TEMP
    float dot = 0.f;
    for (int k = 0; k < 128; ++k) dot += ap[i * 128 + k] * op[j * 128 + k];
    float e = expf(dot * TEMP_INV);
    float maskv = (i == j) ? 1.0f : ((lab[i] == lab[j]) ? 0.5f : 0.0f);
    float num = e * maskv, den = e;
    for (int m = 16; m > 0; m >>= 1) {
        num += __shfl_xor(num, m, 64);
        den += __shfl_xor(den, m, 64);
    }

    // ntxent
    float dn = 0.f;
    for (int k = 0; k < 256; ++k) dn += sp[i * 256 + k] * sp[j * 256 + k];
    float en = expf(dn * TEMP_INV);
    float mnt = (lab[i] == lab[j]) ? ((i == j) ? 0.f : 1.f) : 0.f;
    float pos = en * mnt, neg = en * (1.f - mnt), pc = mnt;
    for (int m = 16; m > 0; m >>= 1) {
        pos += __shfl_xor(pos, m, 64);
        neg += __shfl_xor(neg, m, 64);
        pc += __shfl_xor(pc, m, 64);
    }

    if (j == 0) {
        rowv[i] = -logf(num / den + 1e-8f);
        bool has = pc > 0.f;
        rownt[i] = has ? (-logf(pos / (pos + neg) + 1e-8f) / fmaxf(pc, 1.0f)) : 0.f;
        hp[i] = has ? 1 : 0;
    }
    __syncthreads();
    if (t == 0) {
        float inf = 0.f, nt = 0.f;
        int h = 0;
        for (int q = 0; q < BB; ++q) { inf += rowv[q]; nt += rownt[q]; h += hp[q]; }
        inf /= (float)BB;
        nt /= (float)(h > 0 ? h : 1);
        out[0] = 1.0f * inf + 0.5f * nt;
    }
}

// ---------------------------------------------------------------------------
extern "C" void kernel_launch(void* const* d_in, const int* in_sizes, int n_in,
                              void* d_out, int out_size, void* d_ws, size_t ws_size,
                              hipStream_t stream) {
    const float* span  = (const float*)d_in[0];
    const float* alog  = (const float*)d_in[1];
    const float* olog  = (const float*)d_in[2];
    const int*   labs  = (const int*)d_in[3];
    const float* Wa1   = (const float*)d_in[4];
    const float* ba1   = (const float*)d_in[5];
    const float* Wa2   = (const float*)d_in[6];
    const float* ba2   = (const float*)d_in[7];
    const float* Wo1   = (const float*)d_in[8];
    const float* bo1   = (const float*)d_in[9];
    const float* Wo2   = (const float*)d_in[10];
    const float* bo2   = (const float*)d_in[11];
    const float* Ws1   = (const float*)d_in[12];
    const float* bs1   = (const float*)d_in[13];
    const float* Ws2   = (const float*)d_in[14];
    const float* bs2   = (const float*)d_in[15];

    float* ws = (float*)d_ws;
    float* w_a    = ws;                 // 65536
    float* w_o    = ws + 65536;         // 65536
    float* part_a = ws + 131072;        // 8*32768 = 262144
    float* part_o = ws + 393216;        // 262144
    float* a_emb  = ws + 655360;        // 32768
    float* o_emb  = ws + 688128;        // 32768
    float* a_h    = ws + 720896;        // 16384
    float* o_h    = ws + 737280;        // 16384
    float* a_proj = ws + 753664;        // 4096
    float* o_proj = ws + 757760;        // 4096
    float* s_h    = ws + 761856;        // 32768
    float* s_proj = ws + 794624;        // 8192
    // total: 802816 floats = 3.1 MB

    hipLaunchKernelGGL(pool_weights, dim3(64), dim3(256), 0, stream, alog, olog, w_a, w_o);
    hipLaunchKernelGGL(pool_partial, dim3(256), dim3(256), 0, stream, span, w_a, w_o, part_a, part_o);
    hipLaunchKernelGGL(pool_reduce, dim3(256), dim3(256), 0, stream, part_a, part_o, a_emb, o_emb);
    hipLaunchKernelGGL(layer1_ao, dim3(128), dim3(256), 0, stream,
                       a_emb, o_emb, Wa1, ba1, Wo1, bo1, a_h, o_h);
    hipLaunchKernelGGL(layer2_ao, dim3(64), dim3(128), 0, stream,
                       a_h, o_h, Wa2, ba2, Wo2, bo2, a_proj, o_proj);
    hipLaunchKernelGGL(layer1_s, dim3(128), dim3(256), 0, stream, a_emb, o_emb, Ws1, bs1, s_h);
    hipLaunchKernelGGL(layer2_s, dim3(32), dim3(256), 0, stream, s_h, Ws2, bs2, s_proj);
    hipLaunchKernelGGL(loss_kernel, dim3(1), dim3(1024), 0, stream,
                       a_proj, o_proj, s_proj, labs, (float*)d_out);
}

// Round 2
// 591.720 us; speedup vs baseline: 1.0660x; 1.0660x over previous
//
#include <hip/hip_runtime.h>
#include <hip/hip_bf16.h>

// Problem constants (match reference)
#define BB 32
#define SS 2048
#define HH 1024
#define CC 5
#define TEMP_INV (1.0f/0.07f)

// ---------------------------------------------------------------------------
// K1: pooling weights — softmax over S of sum(logits[:,:,1:5])
// grid: 64 blocks = (b, which), block: 256. LDS-staged coalesced loads.
__global__ void pool_weights(const float* __restrict__ alog,
                             const float* __restrict__ olog,
                             float* __restrict__ w_a,
                             float* __restrict__ w_o) {
    int b = blockIdx.x >> 1;
    int which = blockIdx.x & 1;
    const float* lg = which ? olog : alog;
    float* wout = which ? w_o : w_a;
    __shared__ float raw[SS * CC];   // 40 KB
    __shared__ float sl[SS];         // 8 KB
    __shared__ float red[256];
    int t = threadIdx.x;
    const float4* src = (const float4*)(lg + (size_t)b * SS * CC);
    float4* dst = (float4*)raw;
    for (int i = t; i < SS * CC / 4; i += 256) dst[i] = src[i];
    __syncthreads();
    for (int s = t; s < SS; s += 256) {
        int base = s * 5;
        sl[s] = raw[base + 1] + raw[base + 2] + raw[base + 3] + raw[base + 4];
    }
    __syncthreads();
    float m = -1e30f;
    for (int s = t; s < SS; s += 256) m = fmaxf(m, sl[s]);
    red[t] = m;
    __syncthreads();
    for (int o = 128; o > 0; o >>= 1) {
        if (t < o) red[t] = fmaxf(red[t], red[t + o]);
        __syncthreads();
    }
    m = red[0];
    __syncthreads();
    float sum = 0.f;
    for (int s = t; s < SS; s += 256) {
        float e = expf(sl[s] - m);
        sl[s] = e;
        sum += e;
    }
    red[t] = sum;
    __syncthreads();
    for (int o = 128; o > 0; o >>= 1) {
        if (t < o) red[t] += red[t + o];
        __syncthreads();
    }
    float inv = 1.0f / red[0];
    for (int s = t; s < SS; s += 256) wout[(size_t)b * SS + s] = sl[s] * inv;
}

// ---------------------------------------------------------------------------
// K2: pooling main pass — part[chunk][b][h] = sum over 64 s of span*w
// grid: 1024 = b(32) x chunk(32), block: 256 threads, 4 h each (float4)
// 4 blocks/CU, 16 waves/CU -> enough TLP to hide HBM latency.
__global__ void pool_partial(const float* __restrict__ span,
                             const float* __restrict__ w_a,
                             const float* __restrict__ w_o,
                             float* __restrict__ part_a,
                             float* __restrict__ part_o) {
    int b = blockIdx.x >> 5;
    int chunk = blockIdx.x & 31;
    int t = threadIdx.x;
    __shared__ float wa[64], wo[64];
    int s0 = chunk * 64;
    if (t < 64) {
        wa[t] = w_a[(size_t)b * SS + s0 + t];
        wo[t] = w_o[(size_t)b * SS + s0 + t];
    }
    __syncthreads();
    const float4* sp = (const float4*)span + ((size_t)b * SS + s0) * (HH / 4) + t;
    float4 aa = {0.f, 0.f, 0.f, 0.f};
    float4 oo = {0.f, 0.f, 0.f, 0.f};
    #pragma unroll 8
    for (int ss = 0; ss < 64; ++ss) {
        float4 v = sp[(size_t)ss * (HH / 4)];
        float fa = wa[ss], fo = wo[ss];
        aa.x += v.x * fa; aa.y += v.y * fa; aa.z += v.z * fa; aa.w += v.w * fa;
        oo.x += v.x * fo; oo.y += v.y * fo; oo.z += v.z * fo; oo.w += v.w * fo;
    }
    size_t idx = ((size_t)chunk * BB + b) * HH + (size_t)t * 4;
    *(float4*)(part_a + idx) = aa;
    *(float4*)(part_o + idx) = oo;
}

// K2r: reduce 32 partials -> a_emb/o_emb [32][1024]
// grid: 256, block: 256  (gid 0..65535; which = hi bit)
__global__ void pool_reduce(const float* __restrict__ part_a,
                            const float* __restrict__ part_o,
                            float* __restrict__ a_emb,
                            float* __restrict__ o_emb) {
    int gid = blockIdx.x * 256 + threadIdx.x;
    int which = gid >> 15;
    int r = gid & 32767;
    const float* p = which ? part_o : part_a;
    float s = 0.f;
    #pragma unroll
    for (int c = 0; c < 32; ++c) s += p[(size_t)c * 32768 + r];
    (which ? o_emb : a_emb)[r] = s;
}

// ---------------------------------------------------------------------------
// K3: W-once streaming GEMM partial: part[kb][b][j] over k-chunk of 256.
// grid: (N/64, K/256, nsel). block 256 = 64 j x 4 b-groups x 8 b.
// x element [b][k]: k < split ? x0[b*xstride+k] : x1[b*xstride+k-split]
__global__ void gemm_part(const float* __restrict__ xA0, const float* __restrict__ xA1,
                          const float* __restrict__ WA, float* __restrict__ partA,
                          const float* __restrict__ xB0, const float* __restrict__ xB1,
                          const float* __restrict__ WB, float* __restrict__ partB,
                          int split, int xstride, int N) {
    int which = blockIdx.z;
    const float* x0 = which ? xB0 : xA0;
    const float* x1 = which ? xB1 : xA1;
    const float* W  = which ? WB : WA;
    float* part = which ? partB : partA;
    int k0 = blockIdx.y * 256;
    __shared__ float xs[32][256];   // 32 KB
    int t = threadIdx.x;
    const float* xp = (k0 < split) ? x0 : x1;
    int koff = (k0 < split) ? k0 : (k0 - split);
    #pragma unroll
    for (int i = 0; i < 8; ++i) {
        int f = t + i * 256;        // float4 index into [32][64]
        int b = f >> 6;
        int kk = (f & 63) * 4;
        float4 v = *(const float4*)(xp + (size_t)b * xstride + koff + kk);
        *(float4*)(&xs[b][kk]) = v;
    }
    __syncthreads();
    int jl = t & 63, bg = t >> 6;
    int j = blockIdx.x * 64 + jl;
    float acc[8] = {0.f, 0.f, 0.f, 0.f, 0.f, 0.f, 0.f, 0.f};
    const float* Wp = W + (size_t)k0 * N + j;
    for (int k = 0; k < 256; k += 4) {
        float w0 = Wp[(size_t)(k + 0) * N];
        float w1 = Wp[(size_t)(k + 1) * N];
        float w2 = Wp[(size_t)(k + 2) * N];
        float w3 = Wp[(size_t)(k + 3) * N];
        #pragma unroll
        for (int bi = 0; bi < 8; ++bi) {
            float4 xv = *(const float4*)(&xs[bg * 8 + bi][k]);
            acc[bi] += xv.x * w0 + xv.y * w1 + xv.z * w2 + xv.w * w3;
        }
    }
    float* pp = part + (size_t)blockIdx.y * 32 * N + j;
    #pragma unroll
    for (int bi = 0; bi < 8; ++bi)
        pp[(size_t)(bg * 8 + bi) * N] = acc[bi];
}

// K3f: out[b][j] = relu(bias[j] + sum_kb part[kb][b][j]); N power of 2
__global__ void finish_relu(const float* __restrict__ partA, const float* __restrict__ biasA,
                            float* __restrict__ outA,
                            const float* __restrict__ partB, const float* __restrict__ biasB,
                            float* __restrict__ outB, int KS, int N) {
    int which = blockIdx.y;
    const float* part = which ? partB : partA;
    const float* bias = which ? biasB : biasA;
    float* out = which ? outB : outA;
    int idx = blockIdx.x * 256 + threadIdx.x;   // over 32*N
    float s = bias[idx & (N - 1)];
    for (int kb = 0; kb < KS; ++kb) s += part[(size_t)kb * 32 * N + idx];
    out[idx] = fmaxf(s, 0.f);
}

// ---------------------------------------------------------------------------
// K4: a_proj = l2norm(a_h@Wa2+ba2), same for o   [32][128]
// grid: 64 = which(2) x b(32), block: 128
__global__ void layer2_ao(const float* __restrict__ a_h, const float* __restrict__ o_h,
                          const float* __restrict__ Wa2, const float* __restrict__ ba2,
                          const float* __restrict__ Wo2, const float* __restrict__ bo2,
                          float* __restrict__ a_proj, float* __restrict__ o_proj) {
    int which = blockIdx.x >> 5;
    int b = blockIdx.x & 31;
    const float* h = (which ? o_h : a_h) + (size_t)b * 512;
    const float* W = which ? Wo2 : Wa2;
    const float* bias = which ? bo2 : ba2;
    float* out = (which ? o_proj : a_proj) + (size_t)b * 128;
    __shared__ float x[512];
    __shared__ float red[128];
    int t = threadIdx.x;
    for (int k = t; k < 512; k += 128) x[k] = h[k];
    __syncthreads();
    float acc = bias[t];
    for (int k = 0; k < 512; ++k) acc += x[k] * W[(size_t)k * 128 + t];
    red[t] = acc * acc;
    __syncthreads();
    for (int o = 64; o > 0; o >>= 1) {
        if (t < o) red[t] += red[t + o];
        __syncthreads();
    }
    float n = fmaxf(sqrtf(red[0]), 1e-12f);
    out[t] = acc / n;
}

// K6: s_proj = l2norm(s_h@Ws2+bs2)   [32][256]
// grid: 32, block: 256
__global__ void layer2_s(const float* __restrict__ s_h, const float* __restrict__ Ws2,
                         const float* __restrict__ bs2, float* __restrict__ s_proj) {
    int b = blockIdx.x;
    __shared__ float x[HH];
    __shared__ float red[256];
    int t = threadIdx.x;
    for (int k = t; k < HH; k += 256) x[k] = s_h[(size_t)b * HH + k];
    __syncthreads();
    float acc = bs2[t];
    for (int k = 0; k < HH; ++k) acc += x[k] * Ws2[(size_t)k * 256 + t];
    red[t] = acc * acc;
    __syncthreads();
    for (int o = 128; o > 0; o >>= 1) {
        if (t < o) red[t] += red[t + o];
        __syncthreads();
    }
    float n = fmaxf(sqrtf(red[0]), 1e-12f);
    s_proj[(size_t)b * 256 + t] = acc / n;
}

// ---------------------------------------------------------------------------
// K7: losses. One block, 1024 threads: thread (i,j) = one 32x32 sim entry.
__global__ void loss_kernel(const float* __restrict__ a_proj,
                            const float* __restrict__ o_proj,
                            const float* __restrict__ s_proj,
                            const int* __restrict__ labels,
                            float* __restrict__ out) {
    __shared__ float ap[BB * 128];
    __shared__ float op[BB * 128];
    __shared__ float sp[BB * 256];
    __shared__ float rowv[BB], rownt[BB];
    __shared__ int hp[BB], lab[BB];
    int t = threadIdx.x;
    for (int i = t; i < BB * 128; i += 1024) { ap[i] = a_proj[i]; op[i] = o_proj[i]; }
    for (int i = t; i < BB * 256; i += 1024) sp[i] = s_proj[i];
    if (t < BB) lab[t] = labels[t];
    __syncthreads();
    int i = t >> 5, j = t & 31;

    // re-normalize sp rows (reference calls _l2norm again inside _ntxent)
    float ssq = 0.f;
    for (int k = 0; k < 8; ++k) {
        float v = sp[i * 256 + j * 8 + k];
        ssq += v * v;
    }
    for (int m = 16; m > 0; m >>= 1) ssq += __shfl_xor(ssq, m, 64);
    float inv = 1.0f / fmaxf(sqrtf(ssq), 1e-12f);
    for (int k = j; k < 256; k += 32) sp[i * 256 + k] *= inv;
    __syncthreads();

    // infonce: sim = a_proj @ o_proj.T / TEMP
    float dot = 0.f;
    for (int k = 0; k < 128; ++k) dot += ap[i * 128 + k] * op[j * 128 + k];
    float e = expf(dot * TEMP_INV);
    float maskv = (i == j) ? 1.0f : ((lab[i] == lab[j]) ? 0.5f : 0.0f);
    float num = e * maskv, den = e;
    for (int m = 16; m > 0; m >>= 1) {
        num += __shfl_xor(num, m, 64);
        den += __shfl_xor(den, m, 64);
    }

    // ntxent
    float dn = 0.f;
    for (int k = 0; k < 256; ++k) dn += sp[i * 256 + k] * sp[j * 256 + k];
    float en = expf(dn * TEMP_INV);
    float mnt = (lab[i] == lab[j]) ? ((i == j) ? 0.f : 1.f) : 0.f;
    float pos = en * mnt, neg = en * (1.f - mnt), pc = mnt;
    for (int m = 16; m > 0; m >>= 1) {
        pos += __shfl_xor(pos, m, 64);
        neg += __shfl_xor(neg, m, 64);
        pc += __shfl_xor(pc, m, 64);
    }

    if (j == 0) {
        rowv[i] = -logf(num / den + 1e-8f);
        bool has = pc > 0.f;
        rownt[i] = has ? (-logf(pos / (pos + neg) + 1e-8f) / fmaxf(pc, 1.0f)) : 0.f;
        hp[i] = has ? 1 : 0;
    }
    __syncthreads();
    if (t == 0) {
        float inf = 0.f, nt = 0.f;
        int h = 0;
        for (int q = 0; q < BB; ++q) { inf += rowv[q]; nt += rownt[q]; h += hp[q]; }
        inf /= (float)BB;
        nt /= (float)(h > 0 ? h : 1);
        out[0] = 1.0f * inf + 0.5f * nt;
    }
}

// ---------------------------------------------------------------------------
extern "C" void kernel_launch(void* const* d_in, const int* in_sizes, int n_in,
                              void* d_out, int out_size, void* d_ws, size_t ws_size,
                              hipStream_t stream) {
    const float* span  = (const float*)d_in[0];
    const float* alog  = (const float*)d_in[1];
    const float* olog  = (const float*)d_in[2];
    const int*   labs  = (const int*)d_in[3];
    const float* Wa1   = (const float*)d_in[4];
    const float* ba1   = (const float*)d_in[5];
    const float* Wa2   = (const float*)d_in[6];
    const float* ba2   = (const float*)d_in[7];
    const float* Wo1   = (const float*)d_in[8];
    const float* bo1   = (const float*)d_in[9];
    const float* Wo2   = (const float*)d_in[10];
    const float* bo2   = (const float*)d_in[11];
    const float* Ws1   = (const float*)d_in[12];
    const float* bs1   = (const float*)d_in[13];
    const float* Ws2   = (const float*)d_in[14];
    const float* bs2   = (const float*)d_in[15];

    float* ws = (float*)d_ws;
    float* w_a    = ws;                  // 65536
    float* w_o    = ws + 65536;          // 65536
    float* part_a = ws + 131072;         // 32*32768 = 1048576
    float* part_o = ws + 1179648;        // 1048576
    float* a_emb  = ws + 2228224;        // 32768
    float* o_emb  = ws + 2260992;        // 32768
    float* p1_a   = ws + 2293760;        // 4*32*512 = 65536
    float* p1_o   = ws + 2359296;        // 65536
    float* p1_s   = ws + 2424832;        // 8*32*1024 = 262144
    float* a_h    = ws + 2686976;        // 16384
    float* o_h    = ws + 2703360;        // 16384
    float* s_h    = ws + 2719744;        // 32768
    float* a_proj = ws + 2752512;        // 4096
    float* o_proj = ws + 2756608;        // 4096
    float* s_proj = ws + 2760704;        // 8192
    // total ~11.1 MB

    hipLaunchKernelGGL(pool_weights, dim3(64), dim3(256), 0, stream, alog, olog, w_a, w_o);
    hipLaunchKernelGGL(pool_partial, dim3(1024), dim3(256), 0, stream,
                       span, w_a, w_o, part_a, part_o);
    hipLaunchKernelGGL(pool_reduce, dim3(256), dim3(256), 0, stream,
                       part_a, part_o, a_emb, o_emb);
    // layer1 a+o: K=1024, N=512, z=2
    hipLaunchKernelGGL(gemm_part, dim3(8, 4, 2), dim3(256), 0, stream,
                       a_emb, a_emb, Wa1, p1_a,
                       o_emb, o_emb, Wo1, p1_o,
                       1024, 1024, 512);
    // layer1 s: K=2048 (concat), N=1024
    hipLaunchKernelGGL(gemm_part, dim3(16, 8, 1), dim3(256), 0, stream,
                       a_emb, o_emb, Ws1, p1_s,
                       a_emb, o_emb, Ws1, p1_s,
                       1024, 1024, 1024);
    hipLaunchKernelGGL(finish_relu, dim3(64, 2), dim3(256), 0, stream,
                       p1_a, ba1, a_h, p1_o, bo1, o_h, 4, 512);
    hipLaunchKernelGGL(finish_relu, dim3(128, 1), dim3(256), 0, stream,
                       p1_s, bs1, s_h, p1_s, bs1, s_h, 8, 1024);
    hipLaunchKernelGGL(layer2_ao, dim3(64), dim3(128), 0, stream,
                       a_h, o_h, Wa2, ba2, Wo2, bo2, a_proj, o_proj);
    hipLaunchKernelGGL(layer2_s, dim3(32), dim3(256), 0, stream, s_h, Ws2, bs2, s_proj);
    hipLaunchKernelGGL(loss_kernel, dim3(1), dim3(1024), 0, stream,
                       a_proj, o_proj, s_proj, labs, (float*)d_out);
}

// Round 3
// 530.599 us; speedup vs baseline: 1.1888x; 1.1152x over previous
//
#include <hip/hip_runtime.h>
#include <hip/hip_bf16.h>

// Problem constants (match reference)
#define BB 32
#define SS 2048
#define HH 1024
#define CC 5
#define TEMP_INV (1.0f/0.07f)

// ---------------------------------------------------------------------------
// K1: pooling weights — softmax over S of sum(logits[:,:,1:5])
// grid: 64 blocks = (b, which), block: 256. LDS-staged coalesced loads.
__global__ void pool_weights(const float* __restrict__ alog,
                             const float* __restrict__ olog,
                             float* __restrict__ w_a,
                             float* __restrict__ w_o) {
    int b = blockIdx.x >> 1;
    int which = blockIdx.x & 1;
    const float* lg = which ? olog : alog;
    float* wout = which ? w_o : w_a;
    __shared__ float raw[SS * CC];   // 40 KB
    __shared__ float sl[SS];         // 8 KB
    __shared__ float red[256];
    int t = threadIdx.x;
    const float4* src = (const float4*)(lg + (size_t)b * SS * CC);
    float4* dst = (float4*)raw;
    for (int i = t; i < SS * CC / 4; i += 256) dst[i] = src[i];
    __syncthreads();
    for (int s = t; s < SS; s += 256) {
        int base = s * 5;
        sl[s] = raw[base + 1] + raw[base + 2] + raw[base + 3] + raw[base + 4];
    }
    __syncthreads();
    float m = -1e30f;
    for (int s = t; s < SS; s += 256) m = fmaxf(m, sl[s]);
    red[t] = m;
    __syncthreads();
    for (int o = 128; o > 0; o >>= 1) {
        if (t < o) red[t] = fmaxf(red[t], red[t + o]);
        __syncthreads();
    }
    m = red[0];
    __syncthreads();
    float sum = 0.f;
    for (int s = t; s < SS; s += 256) {
        float e = expf(sl[s] - m);
        sl[s] = e;
        sum += e;
    }
    red[t] = sum;
    __syncthreads();
    for (int o = 128; o > 0; o >>= 1) {
        if (t < o) red[t] += red[t + o];
        __syncthreads();
    }
    float inv = 1.0f / red[0];
    for (int s = t; s < SS; s += 256) wout[(size_t)b * SS + s] = sl[s] * inv;
}

// ---------------------------------------------------------------------------
// K2: pooling main pass — part[chunk][b][h] = sum over 64 s of span*w
// grid: 1024 = b(32) x chunk(32), block: 256 threads, 4 h each (float4)
__global__ void pool_partial(const float* __restrict__ span,
                             const float* __restrict__ w_a,
                             const float* __restrict__ w_o,
                             float* __restrict__ part_a,
                             float* __restrict__ part_o) {
    int b = blockIdx.x >> 5;
    int chunk = blockIdx.x & 31;
    int t = threadIdx.x;
    __shared__ float wa[64], wo[64];
    int s0 = chunk * 64;
    if (t < 64) {
        wa[t] = w_a[(size_t)b * SS + s0 + t];
        wo[t] = w_o[(size_t)b * SS + s0 + t];
    }
    __syncthreads();
    const float4* sp = (const float4*)span + ((size_t)b * SS + s0) * (HH / 4) + t;
    float4 aa = {0.f, 0.f, 0.f, 0.f};
    float4 oo = {0.f, 0.f, 0.f, 0.f};
    #pragma unroll 8
    for (int ss = 0; ss < 64; ++ss) {
        float4 v = sp[(size_t)ss * (HH / 4)];
        float fa = wa[ss], fo = wo[ss];
        aa.x += v.x * fa; aa.y += v.y * fa; aa.z += v.z * fa; aa.w += v.w * fa;
        oo.x += v.x * fo; oo.y += v.y * fo; oo.z += v.z * fo; oo.w += v.w * fo;
    }
    size_t idx = ((size_t)chunk * BB + b) * HH + (size_t)t * 4;
    *(float4*)(part_a + idx) = aa;
    *(float4*)(part_o + idx) = oo;
}

// K2r: reduce 32 partials -> a_emb/o_emb [32][1024]
// grid: 256, block: 256  (gid 0..65535; which = hi bit)
__global__ void pool_reduce(const float* __restrict__ part_a,
                            const float* __restrict__ part_o,
                            float* __restrict__ a_emb,
                            float* __restrict__ o_emb) {
    int gid = blockIdx.x * 256 + threadIdx.x;
    int which = gid >> 15;
    int r = gid & 32767;
    const float* p = which ? part_o : part_a;
    float s = 0.f;
    #pragma unroll
    for (int c = 0; c < 32; ++c) s += p[(size_t)c * 32768 + r];
    (which ? o_emb : a_emb)[r] = s;
}

// ---------------------------------------------------------------------------
// K3: all three layer-1 GEMMs in one launch, W streamed once, k-split partials.
// grid: 192 blocks: [0,32)=a (8j x 4k), [32,64)=o, [64,192)=s (16j x 8k).
// block 256 = 64 j-lanes x 4 b-groups (8 batch rows each).
__global__ void gemm1_all(const float* __restrict__ a_emb, const float* __restrict__ o_emb,
                          const float* __restrict__ Wa1, const float* __restrict__ Wo1,
                          const float* __restrict__ Ws1,
                          float* __restrict__ p1_a, float* __restrict__ p1_o,
                          float* __restrict__ p1_s) {
    int bid = blockIdx.x;
    const float* xp; const float* W; float* part; int N, kb, jb;
    if (bid < 32) {
        jb = bid & 7; kb = bid >> 3; N = 512; W = Wa1; part = p1_a;
        xp = a_emb + kb * 256;
    } else if (bid < 64) {
        int r = bid - 32;
        jb = r & 7; kb = r >> 3; N = 512; W = Wo1; part = p1_o;
        xp = o_emb + kb * 256;
    } else {
        int r = bid - 64;
        jb = r & 15; kb = r >> 4; N = 1024; W = Ws1; part = p1_s;
        int kk0 = kb * 256;
        xp = (kk0 < 1024) ? (a_emb + kk0) : (o_emb + (kk0 - 1024));
    }
    int k0 = kb * 256;   // global k row offset into W
    __shared__ float xs[32][256];   // 32 KB
    int t = threadIdx.x;
    #pragma unroll
    for (int i = 0; i < 8; ++i) {
        int f = t + i * 256;        // float4 index into [32][64]
        int b = f >> 6;
        int kk = (f & 63) * 4;
        *(float4*)(&xs[b][kk]) = *(const float4*)(xp + (size_t)b * HH + kk);
    }
    __syncthreads();
    int jl = t & 63, bg = t >> 6;
    int j = jb * 64 + jl;
    float acc[8] = {0.f, 0.f, 0.f, 0.f, 0.f, 0.f, 0.f, 0.f};
    const float* Wp = W + (size_t)k0 * N + j;
    for (int k = 0; k < 256; k += 4) {
        float w0 = Wp[(size_t)(k + 0) * N];
        float w1 = Wp[(size_t)(k + 1) * N];
        float w2 = Wp[(size_t)(k + 2) * N];
        float w3 = Wp[(size_t)(k + 3) * N];
        #pragma unroll
        for (int bi = 0; bi < 8; ++bi) {
            float4 xv = *(const float4*)(&xs[bg * 8 + bi][k]);
            acc[bi] += xv.x * w0 + xv.y * w1 + xv.z * w2 + xv.w * w3;
        }
    }
    float* pp = part + (size_t)kb * 32 * N + j;
    #pragma unroll
    for (int bi = 0; bi < 8; ++bi)
        pp[(size_t)(bg * 8 + bi) * N] = acc[bi];
}

// ---------------------------------------------------------------------------
// K4: layer 2 for a/o/s, with fused k-split reduction + bias + relu of layer1.
// grid: 96 blocks: [0,32)=a, [32,64)=o, [64,96)=s. block: 256.
__global__ void layer2_all(const float* __restrict__ p1_a, const float* __restrict__ ba1,
                           const float* __restrict__ Wa2, const float* __restrict__ ba2,
                           const float* __restrict__ p1_o, const float* __restrict__ bo1,
                           const float* __restrict__ Wo2, const float* __restrict__ bo2,
                           const float* __restrict__ p1_s, const float* __restrict__ bs1,
                           const float* __restrict__ Ws2, const float* __restrict__ bs2,
                           float* __restrict__ a_proj, float* __restrict__ o_proj,
                           float* __restrict__ s_proj) {
    __shared__ float x[1024];
    __shared__ float red[256];
    int bid = blockIdx.x;
    int t = threadIdx.x;
    if (bid < 64) {
        int which = bid >> 5;
        int b = bid & 31;
        const float* part = which ? p1_o : p1_a;
        const float* b1 = which ? bo1 : ba1;
        const float* W2 = which ? Wo2 : Wa2;
        const float* b2 = which ? bo2 : ba2;
        float* out = (which ? o_proj : a_proj) + (size_t)b * 128;
        for (int j = t; j < 512; j += 256) {
            float s = b1[j];
            #pragma unroll
            for (int kb = 0; kb < 4; ++kb) s += part[(size_t)kb * 32 * 512 + (size_t)b * 512 + j];
            x[j] = fmaxf(s, 0.f);
        }
        __syncthreads();
        float acc = 0.f;
        if (t < 128) {
            acc = b2[t];
            for (int k = 0; k < 512; ++k) acc += x[k] * W2[(size_t)k * 128 + t];
        }
        red[t] = (t < 128) ? acc * acc : 0.f;
        __syncthreads();
        for (int o = 128; o > 0; o >>= 1) {
            if (t < o) red[t] += red[t + o];
            __syncthreads();
        }
        float n = fmaxf(sqrtf(red[0]), 1e-12f);
        if (t < 128) out[t] = acc / n;
    } else {
        int b = bid - 64;
        for (int j = t; j < 1024; j += 256) {
            float s = bs1[j];
            #pragma unroll
            for (int kb = 0; kb < 8; ++kb) s += p1_s[(size_t)kb * 32 * 1024 + (size_t)b * 1024 + j];
            x[j] = fmaxf(s, 0.f);
        }
        __syncthreads();
        float acc = bs2[t];
        for (int k = 0; k < 1024; ++k) acc += x[k] * Ws2[(size_t)k * 256 + t];
        red[t] = acc * acc;
        __syncthreads();
        for (int o = 128; o > 0; o >>= 1) {
            if (t < o) red[t] += red[t + o];
            __syncthreads();
        }
        float n = fmaxf(sqrtf(red[0]), 1e-12f);
        s_proj[(size_t)b * 256 + t] = acc / n;
    }
}

// ---------------------------------------------------------------------------
// K5: losses. One block, 1024 threads: thread (i,j) = one 32x32 sim entry.
__global__ void loss_kernel(const float* __restrict__ a_proj,
                            const float* __restrict__ o_proj,
                            const float* __restrict__ s_proj,
                            const int* __restrict__ labels,
                            float* __restrict__ out) {
    __shared__ float ap[BB * 128];
    __shared__ float op[BB * 128];
    __shared__ float sp[BB * 256];
    __shared__ float rowv[BB], rownt[BB];
    __shared__ int hp[BB], lab[BB];
    int t = threadIdx.x;
    for (int i = t; i < BB * 128; i += 1024) { ap[i] = a_proj[i]; op[i] = o_proj[i]; }
    for (int i = t; i < BB * 256; i += 1024) sp[i] = s_proj[i];
    if (t < BB) lab[t] = labels[t];
    __syncthreads();
    int i = t >> 5, j = t & 31;

    // re-normalize sp rows (reference calls _l2norm again inside _ntxent)
    float ssq = 0.f;
    for (int k = 0; k < 8; ++k) {
        float v = sp[i * 256 + j * 8 + k];
        ssq += v * v;
    }
    for (int m = 16; m > 0; m >>= 1) ssq += __shfl_xor(ssq, m, 64);
    float inv = 1.0f / fmaxf(sqrtf(ssq), 1e-12f);
    for (int k = j; k < 256; k += 32) sp[i * 256 + k] *= inv;
    __syncthreads();

    // infonce: sim = a_proj @ o_proj.T / TEMP
    float dot = 0.f;
    for (int k = 0; k < 128; ++k) dot += ap[i * 128 + k] * op[j * 128 + k];
    float e = expf(dot * TEMP_INV);
    float maskv = (i == j) ? 1.0f : ((lab[i] == lab[j]) ? 0.5f : 0.0f);
    float num = e * maskv, den = e;
    for (int m = 16; m > 0; m >>= 1) {
        num += __shfl_xor(num, m, 64);
        den += __shfl_xor(den, m, 64);
    }

    // ntxent
    float dn = 0.f;
    for (int k = 0; k < 256; ++k) dn += sp[i * 256 + k] * sp[j * 256 + k];
    float en = expf(dn * TEMP_INV);
    float mnt = (lab[i] == lab[j]) ? ((i == j) ? 0.f : 1.f) : 0.f;
    float pos = en * mnt, neg = en * (1.f - mnt), pc = mnt;
    for (int m = 16; m > 0; m >>= 1) {
        pos += __shfl_xor(pos, m, 64);
        neg += __shfl_xor(neg, m, 64);
        pc += __shfl_xor(pc, m, 64);
    }

    if (j == 0) {
        rowv[i] = -logf(num / den + 1e-8f);
        bool has = pc > 0.f;
        rownt[i] = has ? (-logf(pos / (pos + neg) + 1e-8f) / fmaxf(pc, 1.0f)) : 0.f;
        hp[i] = has ? 1 : 0;
    }
    __syncthreads();
    if (t == 0) {
        float inf = 0.f, nt = 0.f;
        int h = 0;
        for (int q = 0; q < BB; ++q) { inf += rowv[q]; nt += rownt[q]; h += hp[q]; }
        inf /= (float)BB;
        nt /= (float)(h > 0 ? h : 1);
        out[0] = 1.0f * inf + 0.5f * nt;
    }
}

// ---------------------------------------------------------------------------
extern "C" void kernel_launch(void* const* d_in, const int* in_sizes, int n_in,
                              void* d_out, int out_size, void* d_ws, size_t ws_size,
                              hipStream_t stream) {
    const float* span  = (const float*)d_in[0];
    const float* alog  = (const float*)d_in[1];
    const float* olog  = (const float*)d_in[2];
    const int*   labs  = (const int*)d_in[3];
    const float* Wa1   = (const float*)d_in[4];
    const float* ba1   = (const float*)d_in[5];
    const float* Wa2   = (const float*)d_in[6];
    const float* ba2   = (const float*)d_in[7];
    const float* Wo1   = (const float*)d_in[8];
    const float* bo1   = (const float*)d_in[9];
    const float* Wo2   = (const float*)d_in[10];
    const float* bo2   = (const float*)d_in[11];
    const float* Ws1   = (const float*)d_in[12];
    const float* bs1   = (const float*)d_in[13];
    const float* Ws2   = (const float*)d_in[14];
    const float* bs2   = (const float*)d_in[15];

    float* ws = (float*)d_ws;
    float* w_a    = ws;                  // 65536
    float* w_o    = ws + 65536;          // 65536
    float* part_a = ws + 131072;         // 32*32768 = 1048576
    float* part_o = ws + 1179648;        // 1048576
    float* a_emb  = ws + 2228224;        // 32768
    float* o_emb  = ws + 2260992;        // 32768
    float* p1_a   = ws + 2293760;        // 4*32*512 = 65536
    float* p1_o   = ws + 2359296;        // 65536
    float* p1_s   = ws + 2424832;        // 8*32*1024 = 262144
    float* a_proj = ws + 2686976;        // 4096
    float* o_proj = ws + 2691072;        // 4096
    float* s_proj = ws + 2695168;        // 8192

    hipLaunchKernelGGL(pool_weights, dim3(64), dim3(256), 0, stream, alog, olog, w_a, w_o);
    hipLaunchKernelGGL(pool_partial, dim3(1024), dim3(256), 0, stream,
                       span, w_a, w_o, part_a, part_o);
    hipLaunchKernelGGL(pool_reduce, dim3(256), dim3(256), 0, stream,
                       part_a, part_o, a_emb, o_emb);
    hipLaunchKernelGGL(gemm1_all, dim3(192), dim3(256), 0, stream,
                       a_emb, o_emb, Wa1, Wo1, Ws1, p1_a, p1_o, p1_s);
    hipLaunchKernelGGL(layer2_all, dim3(96), dim3(256), 0, stream,
                       p1_a, ba1, Wa2, ba2, p1_o, bo1, Wo2, bo2,
                       p1_s, bs1, Ws2, bs2, a_proj, o_proj, s_proj);
    hipLaunchKernelGGL(loss_kernel, dim3(1), dim3(1024), 0, stream,
                       a_proj, o_proj, s_proj, labs, (float*)d_out);
}